// Round 1
// baseline (121.357 us; speedup 1.0000x reference)
//
#include <hip/hip_runtime.h>

#define B_   256
#define E_   64
#define G_   2000
#define P_   512
#define K2   2016      // G padded up to a multiple of BK
#define BN   64
#define BK   32
#define NS   (K2/BK)   // 63 K-steps
#define WPAD 40        // LDS row pitch in bf16 (80 B) -> uniform bank spread

typedef __bf16 bf16x8 __attribute__((ext_vector_type(8)));
typedef float floatx4 __attribute__((ext_vector_type(4)));

__global__ __launch_bounds__(256)
void cvt_x_kernel(const float* __restrict__ x, __bf16* __restrict__ xb) {
    int col = blockIdx.x * 256 + threadIdx.x;
    int row = blockIdx.y;
    if (col < K2) {
        float v = (col < G_) ? x[(size_t)row * G_ + col] : 0.f;
        xb[(size_t)row * K2 + col] = (__bf16)v;
    }
}

template<bool USE_WS>
__global__ __launch_bounds__(256, 2)
void masked_gemm_kernel(const float* __restrict__ x,
                        const __bf16* __restrict__ xb,
                        const float* __restrict__ weight,
                        const float* __restrict__ bias,
                        const float* __restrict__ mask,
                        float* __restrict__ out)
{
    __shared__ __bf16 wlds[2][BN][WPAD];   // [buf][n][k], transposed weight*mask tile

    const int tid = threadIdx.x;
    const int bid = blockIdx.x;          // 512 blocks
    // XCD-aware: round-robin bid%8 -> XCD, so XCD i owns N-slab i (mask/x stay L2-hot)
    const int nt = bid & 7;              // N tile 0..7
    const int e  = bid >> 3;             // 0..63
    const int p0 = nt * BN;

    const int lane = tid & 63;
    const int wv   = tid >> 6;           // wave 0..3 -> rows wv*64..wv*64+63
    const int ln   = lane & 15;
    const int hi   = lane >> 4;          // k-slot group 0..3

    // staging coords: wave so handles k-octet so, lane sp = p-local
    const int so = tid >> 6;
    const int sp = tid & 63;

    const float* wbase = weight + (size_t)e * G_ * P_ + p0 + sp;
    const float* mbase = mask + p0 + sp;

    floatx4 acc[4][4];
    #pragma unroll
    for (int i = 0; i < 4; ++i)
        #pragma unroll
        for (int j = 0; j < 4; ++j)
            acc[i][j] = (floatx4)0.f;

    float wr[8], mr[8];

    // prologue: stage K-step 0 into buffer 0 (g 0..31 all valid)
    {
        #pragma unroll
        for (int j = 0; j < 8; ++j) {
            wr[j] = wbase[(size_t)(so * 8 + j) * P_];
            mr[j] = mbase[(size_t)(so * 8 + j) * P_];
        }
        bf16x8 h;
        #pragma unroll
        for (int j = 0; j < 8; ++j) h[j] = (__bf16)(wr[j] * mr[j]);
        *(bf16x8*)&wlds[0][sp][so * 8] = h;
    }

    const int mrow0 = wv * 64;

    for (int s = 0; s < NS; ++s) {
        const int cur = s & 1;
        const int kb = s * BK;
        const bool more = (s + 1 < NS);

        __syncthreads();                       // buffer `cur` ready

        // issue global loads for next K-step (overlap with MFMA below)
        bool sval = false;
        if (more) {
            const int g0 = kb + BK + so * 8;   // 2000 % 8 == 0 -> octet fully valid or not
            sval = (g0 < G_);
            if (sval) {
                #pragma unroll
                for (int j = 0; j < 8; ++j) {
                    wr[j] = wbase[(size_t)(g0 + j) * P_];
                    mr[j] = mbase[(size_t)(g0 + j) * P_];
                }
            }
        }

        // compute on buffer cur
        bf16x8 bfrag[4];
        #pragma unroll
        for (int ni = 0; ni < 4; ++ni)
            bfrag[ni] = *(const bf16x8*)&wlds[cur][ni * 16 + ln][hi * 8];

        bf16x8 afrag[4];
        if (USE_WS) {
            #pragma unroll
            for (int mi = 0; mi < 4; ++mi) {
                const int row = mrow0 + mi * 16 + ln;
                afrag[mi] = *(const bf16x8*)&xb[(size_t)row * K2 + kb + hi * 8];
            }
        } else {
            #pragma unroll
            for (int mi = 0; mi < 4; ++mi) {
                const int row = mrow0 + mi * 16 + ln;
                const int k = kb + hi * 8;
                bf16x8 a;
                if (k + 8 <= G_) {
                    float4 f0 = *(const float4*)&x[(size_t)row * G_ + k];
                    float4 f1 = *(const float4*)&x[(size_t)row * G_ + k + 4];
                    a[0]=(__bf16)f0.x; a[1]=(__bf16)f0.y; a[2]=(__bf16)f0.z; a[3]=(__bf16)f0.w;
                    a[4]=(__bf16)f1.x; a[5]=(__bf16)f1.y; a[6]=(__bf16)f1.z; a[7]=(__bf16)f1.w;
                } else {
                    #pragma unroll
                    for (int j = 0; j < 8; ++j) a[j] = (__bf16)0.f;
                }
                afrag[mi] = a;
            }
        }

        #pragma unroll
        for (int mi = 0; mi < 4; ++mi)
            #pragma unroll
            for (int ni = 0; ni < 4; ++ni)
                acc[mi][ni] = __builtin_amdgcn_mfma_f32_16x16x32_bf16(
                                  afrag[mi], bfrag[ni], acc[mi][ni], 0, 0, 0);

        // convert + transposed write of next tile (waits the global loads here)
        if (more) {
            bf16x8 h;
            if (sval) {
                #pragma unroll
                for (int j = 0; j < 8; ++j) h[j] = (__bf16)(wr[j] * mr[j]);
            } else {
                #pragma unroll
                for (int j = 0; j < 8; ++j) h[j] = (__bf16)0.f;
            }
            *(bf16x8*)&wlds[cur ^ 1][sp][so * 8] = h;
        }
    }

    // epilogue: D[row=(lane>>4)*4+j][col=lane&15], add bias, nontemporal stores
    #pragma unroll
    for (int ni = 0; ni < 4; ++ni) {
        const int p = p0 + ni * 16 + ln;
        const float bv = bias[e * P_ + p];
        #pragma unroll
        for (int mi = 0; mi < 4; ++mi) {
            #pragma unroll
            for (int j = 0; j < 4; ++j) {
                const int b = mrow0 + mi * 16 + hi * 4 + j;
                __builtin_nontemporal_store(acc[mi][ni][j] + bv,
                    &out[(size_t)b * (E_ * P_) + (size_t)e * P_ + p]);
            }
        }
    }
}

extern "C" void kernel_launch(void* const* d_in, const int* in_sizes, int n_in,
                              void* d_out, int out_size, void* d_ws, size_t ws_size,
                              hipStream_t stream) {
    const float* x      = (const float*)d_in[0];
    const float* weight = (const float*)d_in[1];
    const float* bias   = (const float*)d_in[2];
    const float* mask   = (const float*)d_in[3];
    float* out = (float*)d_out;

    const size_t xb_bytes = (size_t)B_ * K2 * sizeof(__bf16);
    if (ws_size >= xb_bytes) {
        __bf16* xb = (__bf16*)d_ws;
        dim3 g1((K2 + 255) / 256, B_);
        cvt_x_kernel<<<g1, dim3(256), 0, stream>>>(x, xb);
        masked_gemm_kernel<true><<<dim3(512), dim3(256), 0, stream>>>(x, xb, weight, bias, mask, out);
    } else {
        masked_gemm_kernel<false><<<dim3(512), dim3(256), 0, stream>>>(x, nullptr, weight, bias, mask, out);
    }
}